// Round 1
// baseline (20628.622 us; speedup 1.0000x reference)
//
#include <hip/hip_runtime.h>
#include <hip/hip_bf16.h>
#include <math.h>

// Problem constants
#define BB 64
#define NPIX 196
#define ENCD 2048
#define DECD 512
#define ATTD 512
#define EMBD 512
#define VOCAB_N 10000
#define MAXLEN 52
#define TT 51   // MAXLEN-1 decode steps

// Output layout (floats): preds | captions | declens | alphas
#define PRED_SZ   (BB * TT * VOCAB_N)          // 32,640,000
#define CAPS_SZ   (BB * MAXLEN)                // 3,328
#define LENS_SZ   (BB)                         // 64
#define ALPHAS_OFF (PRED_SZ + CAPS_SZ + LENS_SZ) // 32,643,392

__device__ __forceinline__ float fsigm(float x) {
    return 1.0f / (1.0f + __expf(-x));
}
__device__ __forceinline__ float ftanh(float x) {
    x = fminf(fmaxf(x, -15.0f), 15.0f);
    float e = __expf(2.0f * x);
    return (e - 1.0f) / (e + 1.0f);
}

// ---------------------------------------------------------------------------
// Generic LDS-tiled GEMM body: C[M,N] = act(A[M,K] @ W[K,N] + bias) * rowmask
// Tile 64x64, 256 threads, BK=16. K must be a multiple of 16, M of 64.
// ---------------------------------------------------------------------------
__device__ __forceinline__ void gemm_body(
    const float* __restrict__ A, int lda,
    const float* __restrict__ W, int ldw,
    float* __restrict__ C, long ldc,
    const float* __restrict__ bias,
    int M, int N, int K, int act,
    const int* __restrict__ caplen, int t,
    int n0, int m0)
{
    __shared__ float As[16][65];   // As[k][r], padded to break bank conflicts
    __shared__ float Ws[16][64];   // Ws[k][c]
    const int tid = threadIdx.x;
    const int cc = tid & 63;       // column within tile
    const int rg = tid >> 6;       // wave id -> row group (16 rows each)
    const int ka = tid & 15;       // staging k for A
    const int ra = tid >> 4;       // staging row base for A
    const int kw = tid >> 6;       // staging k base for W
    const bool nok = (n0 + cc) < N;

    float acc[16];
#pragma unroll
    for (int i = 0; i < 16; ++i) acc[i] = 0.0f;

    for (int k0 = 0; k0 < K; k0 += 16) {
#pragma unroll
        for (int i = 0; i < 4; ++i)
            As[ka][ra + 16 * i] = A[(size_t)(m0 + ra + 16 * i) * lda + (k0 + ka)];
#pragma unroll
        for (int i = 0; i < 4; ++i)
            Ws[kw + 4 * i][cc] = nok ? W[(size_t)(k0 + kw + 4 * i) * ldw + (n0 + cc)] : 0.0f;
        __syncthreads();
#pragma unroll
        for (int kk = 0; kk < 16; ++kk) {
            float w = Ws[kk][cc];
#pragma unroll
            for (int i = 0; i < 16; ++i)
                acc[i] += As[kk][rg * 16 + i] * w;
        }
        __syncthreads();
    }

    if (nok) {
        float bv = bias ? bias[n0 + cc] : 0.0f;
#pragma unroll
        for (int i = 0; i < 16; ++i) {
            int r = rg * 16 + i;
            float v = acc[i] + bv;
            if (act == 1) v = fsigm(v);
            if (caplen) v *= (t < caplen[m0 + r] - 1) ? 1.0f : 0.0f;
            C[(size_t)(m0 + r) * ldc + (n0 + cc)] = v;
        }
    }
}

__global__ __launch_bounds__(256) void gemm_kernel(
    const float* __restrict__ A, int lda,
    const float* __restrict__ W, int ldw,
    float* __restrict__ C, long ldc,
    const float* __restrict__ bias,
    int M, int N, int K, int act,
    const int* __restrict__ caplen, int t)
{
    gemm_body(A, lda, W, ldw, C, ldc, bias, M, N, K, act, caplen, t,
              blockIdx.x * 64, blockIdx.y * 64);
}

// gates partials: slot<5 -> xcat chunk @ W_ih chunk ; slot==5 -> h @ W_hh
__global__ __launch_bounds__(256) void gates_kernel(
    const float* __restrict__ xcat, const float* __restrict__ h,
    const float* __restrict__ Wih, const float* __restrict__ Whh,
    float* __restrict__ parts)
{
    int slot = blockIdx.y;
    const float* A;
    int lda;
    const float* W;
    if (slot < 5) {
        A = xcat + slot * 512;
        lda = 2560;
        W = Wih + (size_t)slot * 512 * 2048;
    } else {
        A = h;
        lda = 512;
        W = Whh;
    }
    gemm_body(A, lda, W, 2048, parts + (size_t)slot * BB * 2048, 2048,
              nullptr, BB, 2048, 512, 0, nullptr, 0, blockIdx.x * 64, 0);
}

// ---------------------------------------------------------------------------
// Setup kernels
// ---------------------------------------------------------------------------
__global__ void mean_kernel(const float* __restrict__ enc, float* __restrict__ me)
{
    int d = blockIdx.x * 256 + threadIdx.x;   // 0..2047
    int b = blockIdx.y;
    const float* p = enc + (size_t)b * NPIX * ENCD + d;
    float s = 0.0f;
    for (int q = 0; q < NPIX; ++q) s += p[(size_t)q * ENCD];
    me[b * ENCD + d] = s * (1.0f / 196.0f);
}

__global__ void inithc_kernel(const float* __restrict__ me,
                              const float* __restrict__ Wh, const float* __restrict__ bh,
                              const float* __restrict__ Wc, const float* __restrict__ bc,
                              float* __restrict__ h, float* __restrict__ c)
{
    int idx = blockIdx.x * 256 + threadIdx.x;  // 0..32767
    int b = idx >> 9, j = idx & 511;
    const float* m = me + b * ENCD;
    float sh = bh[j], sc = bc[j];
    for (int k = 0; k < ENCD; ++k) {
        float mv = m[k];
        sh += mv * Wh[(size_t)k * DECD + j];
        sc += mv * Wc[(size_t)k * DECD + j];
    }
    h[idx] = sh;
    c[idx] = sc;
}

__global__ void copy_misc(const int* __restrict__ caps, const int* __restrict__ lens,
                          float* __restrict__ out)
{
    int i = blockIdx.x * 256 + threadIdx.x;
    if (i < CAPS_SZ) out[PRED_SZ + i] = (float)caps[i];
    else if (i < CAPS_SZ + LENS_SZ) out[PRED_SZ + i] = (float)(lens[i - CAPS_SZ] - 1);
}

// ---------------------------------------------------------------------------
// Fused attention: att_dec = h@Wd + bd ; e = tanh(att_enc + att_dec)@Wf + bf ;
// alpha = softmax(e) ; write alpha to ws and masked alpha to out.
// One block per batch row.
// ---------------------------------------------------------------------------
__global__ __launch_bounds__(256) void att_kernel(
    const float* __restrict__ h,
    const float* __restrict__ Wd, const float* __restrict__ bd,
    const float* __restrict__ att_enc,
    const float* __restrict__ Wf, const float* __restrict__ bf,
    const int* __restrict__ caplen, int t,
    float* __restrict__ alpha_ws, float* __restrict__ alphas_out)
{
    int b = blockIdx.x;
    int tid = threadIdx.x;
    int lane = tid & 63, wid = tid >> 6;
    __shared__ float hs[512];
    __shared__ float adec[512];
    __shared__ float es[196];
    __shared__ float r4[4];
    __shared__ float smax, ssum;

    for (int j = tid; j < 512; j += 256) hs[j] = h[b * 512 + j];
    __syncthreads();

    for (int j = tid; j < 512; j += 256) {
        float s = bd[j];
        for (int k = 0; k < 512; ++k) s += hs[k] * Wd[(size_t)k * 512 + j];
        adec[j] = s;
    }
    __syncthreads();

    for (int p = wid; p < NPIX; p += 4) {
        const float* ae = att_enc + ((size_t)(b * NPIX + p)) * 512;
        float s = 0.0f;
        for (int j = lane; j < 512; j += 64)
            s += ftanh(ae[j] + adec[j]) * Wf[j];
        for (int off = 32; off; off >>= 1) s += __shfl_down(s, off);
        if (lane == 0) es[p] = s + bf[0];
    }
    __syncthreads();

    // softmax over 196
    float v = (tid < NPIX) ? es[tid] : -1e30f;
    float m = v;
    for (int off = 32; off; off >>= 1) m = fmaxf(m, __shfl_down(m, off));
    if (lane == 0) r4[wid] = m;
    __syncthreads();
    if (tid == 0) smax = fmaxf(fmaxf(r4[0], r4[1]), fmaxf(r4[2], r4[3]));
    __syncthreads();

    float ev = (tid < NPIX) ? __expf(v - smax) : 0.0f;
    float s = ev;
    for (int off = 32; off; off >>= 1) s += __shfl_down(s, off);
    if (lane == 0) r4[wid] = s;
    __syncthreads();
    if (tid == 0) ssum = r4[0] + r4[1] + r4[2] + r4[3];
    __syncthreads();

    if (tid < NPIX) {
        float a = ev / ssum;
        alpha_ws[b * NPIX + tid] = a;
        float mk = (t < caplen[b] - 1) ? 1.0f : 0.0f;
        alphas_out[((size_t)b * TT + t) * NPIX + tid] = a * mk;
    }
}

// ---------------------------------------------------------------------------
// Fused awe + gate apply + embedding gather into xcat = [emb_t | gate*awe]
// grid (9, 64): x<8 -> 256-wide chunk of d, x==8 -> embedding copy
// ---------------------------------------------------------------------------
__global__ __launch_bounds__(256) void awe_kernel(
    const float* __restrict__ enc, const float* __restrict__ alpha,
    const float* __restrict__ gatebuf,
    const float* __restrict__ emb, const int* __restrict__ caps, int t,
    float* __restrict__ xcat)
{
    int b = blockIdx.y;
    int x = blockIdx.x;
    int tid = threadIdx.x;
    if (x == 8) {
        int w = caps[b * MAXLEN + t];
        for (int j = tid; j < EMBD; j += 256)
            xcat[(size_t)b * 2560 + j] = emb[(size_t)w * EMBD + j];
        return;
    }
    __shared__ float as[NPIX];
    if (tid < NPIX) as[tid] = alpha[b * NPIX + tid];
    __syncthreads();
    int d = x * 256 + tid;
    const float* e = enc + (size_t)b * NPIX * ENCD + d;
    float s = 0.0f;
    for (int p = 0; p < NPIX; ++p) s += as[p] * e[(size_t)p * ENCD];
    xcat[(size_t)b * 2560 + 512 + d] = gatebuf[b * ENCD + d] * s;
}

// ---------------------------------------------------------------------------
// LSTM cell: reduce 6 partial slots + biases, gate math, masked h/c update
// ---------------------------------------------------------------------------
__global__ __launch_bounds__(256) void lstm_kernel(
    const float* __restrict__ parts,
    const float* __restrict__ bih, const float* __restrict__ bhh,
    const int* __restrict__ caplen, int t,
    float* __restrict__ h, float* __restrict__ c)
{
    int idx = blockIdx.x * 256 + threadIdx.x;  // 0..32767
    int b = idx >> 9, j = idx & 511;

    float gi = bih[j] + bhh[j];
    float gf = bih[512 + j] + bhh[512 + j];
    float gg = bih[1024 + j] + bhh[1024 + j];
    float go = bih[1536 + j] + bhh[1536 + j];
#pragma unroll
    for (int s = 0; s < 6; ++s) {
        const float* p = parts + (size_t)s * BB * 2048 + b * 2048;
        gi += p[j];
        gf += p[512 + j];
        gg += p[1024 + j];
        go += p[1536 + j];
    }
    float cn = fsigm(gf) * c[idx] + fsigm(gi) * ftanh(gg);
    float hn = fsigm(go) * ftanh(cn);
    if (t < caplen[b] - 1) {
        h[idx] = hn;
        c[idx] = cn;
    }
}

// ---------------------------------------------------------------------------
extern "C" void kernel_launch(void* const* d_in, const int* in_sizes, int n_in,
                              void* d_out, int out_size, void* d_ws, size_t ws_size,
                              hipStream_t stream)
{
    const float* enc        = (const float*)d_in[0];
    const int*   caps       = (const int*)d_in[1];
    const int*   lens       = (const int*)d_in[2];
    const float* emb        = (const float*)d_in[3];
    const float* W_enc_att  = (const float*)d_in[4];
    const float* b_enc_att  = (const float*)d_in[5];
    const float* W_dec_att  = (const float*)d_in[6];
    const float* b_dec_att  = (const float*)d_in[7];
    const float* W_full_att = (const float*)d_in[8];
    const float* b_full_att = (const float*)d_in[9];
    const float* W_init_h   = (const float*)d_in[10];
    const float* b_init_h   = (const float*)d_in[11];
    const float* W_init_c   = (const float*)d_in[12];
    const float* b_init_c   = (const float*)d_in[13];
    const float* W_fbeta    = (const float*)d_in[14];
    const float* b_fbeta    = (const float*)d_in[15];
    const float* W_ih       = (const float*)d_in[16];
    const float* W_hh       = (const float*)d_in[17];
    const float* b_ih       = (const float*)d_in[18];
    const float* b_hh       = (const float*)d_in[19];
    const float* W_fc       = (const float*)d_in[20];
    const float* b_fc       = (const float*)d_in[21];
    float* out = (float*)d_out;

    float* ws = (float*)d_ws;
    float* me      = ws;                        // 64*2048
    float* h       = me + BB * ENCD;            // 64*512
    float* c       = h + BB * DECD;             // 64*512
    float* att_enc = c + BB * DECD;             // 64*196*512
    float* alpha   = att_enc + (size_t)BB * NPIX * ATTD;  // 64*196
    float* gatebuf = alpha + BB * NPIX;         // 64*2048
    float* xcat    = gatebuf + BB * ENCD;       // 64*2560
    float* parts   = xcat + BB * 2560;          // 6*64*2048

    // ---- setup ----
    mean_kernel<<<dim3(8, 64), 256, 0, stream>>>(enc, me);
    inithc_kernel<<<128, 256, 0, stream>>>(me, W_init_h, b_init_h, W_init_c, b_init_c, h, c);
    gemm_kernel<<<dim3(8, 196), 256, 0, stream>>>(enc, ENCD, W_enc_att, ATTD,
                                                  att_enc, ATTD, b_enc_att,
                                                  BB * NPIX, ATTD, ENCD, 0, nullptr, 0);
    copy_misc<<<14, 256, 0, stream>>>(caps, lens, out);

    // ---- decode loop ----
    for (int t = 0; t < TT; ++t) {
        // gate = sigmoid(h @ W_fbeta + b_fbeta)
        gemm_kernel<<<dim3(32, 1), 256, 0, stream>>>(h, DECD, W_fbeta, ENCD,
                                                     gatebuf, ENCD, b_fbeta,
                                                     BB, ENCD, DECD, 1, nullptr, 0);
        // attention: alpha + masked alphas output
        att_kernel<<<64, 256, 0, stream>>>(h, W_dec_att, b_dec_att, att_enc,
                                           W_full_att, b_full_att, lens, t,
                                           alpha, out + ALPHAS_OFF);
        // xcat = [emb_t | gate * (alpha . enc)]
        awe_kernel<<<dim3(9, 64), 256, 0, stream>>>(enc, alpha, gatebuf, emb, caps, t, xcat);
        // gates partials: xcat@W_ih (5 slots) + h@W_hh (slot 5)
        gates_kernel<<<dim3(32, 6), 256, 0, stream>>>(xcat, h, W_ih, W_hh, parts);
        // LSTM cell + masked state update
        lstm_kernel<<<128, 256, 0, stream>>>(parts, b_ih, b_hh, lens, t, h, c);
        // preds = (h @ W_fc + b_fc) * mask  -> out[b][t][:]
        gemm_kernel<<<dim3(157, 1), 256, 0, stream>>>(h, DECD, W_fc, VOCAB_N,
                                                      out + (size_t)t * VOCAB_N,
                                                      (long)TT * VOCAB_N, b_fc,
                                                      BB, VOCAB_N, DECD, 0, lens, t);
    }
}

// Round 2
// 5308.661 us; speedup vs baseline: 3.8858x; 3.8858x over previous
//
#include <hip/hip_runtime.h>
#include <hip/hip_bf16.h>
#include <math.h>

#define BB 64
#define NPIX 196
#define ENCD 2048
#define DECD 512
#define VOCAB_N 10000
#define MAXLEN 52
#define TT 51
#define NPADFC 10048

// Output layout (floats): preds | captions | declens | alphas
#define PRED_SZ   (BB * TT * VOCAB_N)
#define CAPS_SZ   (BB * MAXLEN)
#define LENS_SZ   (BB)
#define ALPHAS_OFF (PRED_SZ + CAPS_SZ + LENS_SZ)

typedef __attribute__((ext_vector_type(8))) short short8;
typedef __attribute__((ext_vector_type(4))) float f32x4;

__device__ __forceinline__ float fsigm(float x) {
    return 1.0f / (1.0f + __expf(-x));
}
__device__ __forceinline__ float ftanh(float x) {
    x = fminf(fmaxf(x, -15.0f), 15.0f);
    float e = __expf(2.0f * x);
    return (e - 1.0f) / (e + 1.0f);
}
__device__ __forceinline__ float bf2f(unsigned short u) {
    union { unsigned int i; float f; } v;
    v.i = ((unsigned int)u) << 16;
    return v.f;
}
__device__ __forceinline__ unsigned short f2bf(float f) {
    union { float f; unsigned int i; } v;
    v.f = f;
    unsigned int r = v.i + 0x7FFFu + ((v.i >> 16) & 1u);
    return (unsigned short)(r >> 16);
}

// ---------------------------------------------------------------------------
// MFMA GEMM: C[M,N] = act(A[M,K_slice] @ Wp + bias) (row-masked), bf16 in,
// fp32 acc. A row-major bf16 (lda elems). Wp packed: Wp[kb][n][kk], kk=0..31.
// Block = 4 waves; wave w covers rows m0+16w..+15, cols n0..n0+63 (4 frags).
// blockIdx.z = K-slice (nkb k-blocks each); multi-slice writes partials to
// C + z*slice_stride (bias must be null in that case).
// ---------------------------------------------------------------------------
__global__ __launch_bounds__(256) void gemm_mfma(
    const unsigned short* __restrict__ A, int lda,
    const unsigned short* __restrict__ Wp, int Npad,
    int nkb, long slice_stride,
    float* __restrict__ C, unsigned short* __restrict__ C16, long ldc,
    const float* __restrict__ bias, int N, int act,
    const int* __restrict__ caplen, int t)
{
    const int n0 = blockIdx.x * 64;
    const int m0 = blockIdx.y * 64;
    const int kz = blockIdx.z;
    A  += (size_t)kz * nkb * 32;
    Wp += (size_t)kz * nkb * Npad * 32;
    if (C) C += (size_t)kz * slice_stride;

    const int w  = threadIdx.x >> 6;
    const int l  = threadIdx.x & 63;
    const int lr = l & 15;   // A-row / B-col / D-col within 16-tile
    const int q  = l >> 4;   // k sub-block: k = q*8 + j

    const unsigned short* ap = A + (size_t)(m0 + 16 * w + lr) * lda + q * 8;
    const unsigned short* bp = Wp + (size_t)(n0 + lr) * 32 + q * 8;
    const size_t bstep = (size_t)Npad * 32;

    f32x4 acc[4];
#pragma unroll
    for (int i = 0; i < 4; ++i) acc[i] = (f32x4){0.f, 0.f, 0.f, 0.f};

    short8 a  = *(const short8*)ap;
    short8 b0 = *(const short8*)(bp);
    short8 b1 = *(const short8*)(bp + 512);
    short8 b2 = *(const short8*)(bp + 1024);
    short8 b3 = *(const short8*)(bp + 1536);

    for (int kb = 0; kb < nkb; ++kb) {
        const size_t nxt = (kb + 1 < nkb) ? 1 : 0;
        const unsigned short* apn = ap + nxt * 32;
        const unsigned short* bpn = bp + nxt * bstep;
        short8 an  = *(const short8*)apn;
        short8 bn0 = *(const short8*)(bpn);
        short8 bn1 = *(const short8*)(bpn + 512);
        short8 bn2 = *(const short8*)(bpn + 1024);
        short8 bn3 = *(const short8*)(bpn + 1536);
        acc[0] = __builtin_amdgcn_mfma_f32_16x16x32_bf16(a, b0, acc[0], 0, 0, 0);
        acc[1] = __builtin_amdgcn_mfma_f32_16x16x32_bf16(a, b1, acc[1], 0, 0, 0);
        acc[2] = __builtin_amdgcn_mfma_f32_16x16x32_bf16(a, b2, acc[2], 0, 0, 0);
        acc[3] = __builtin_amdgcn_mfma_f32_16x16x32_bf16(a, b3, acc[3], 0, 0, 0);
        a = an; b0 = bn0; b1 = bn1; b2 = bn2; b3 = bn3;
        ap = apn; bp = bpn;
    }

    const int r0 = q * 4;
#pragma unroll
    for (int cf = 0; cf < 4; ++cf) {
        int col = n0 + cf * 16 + lr;
        if (col >= N) continue;
        float bv = bias ? bias[col] : 0.f;
#pragma unroll
        for (int r = 0; r < 4; ++r) {
            int row = m0 + 16 * w + r0 + r;
            float v = acc[cf][r] + bv;
            if (act == 1 || (act == 2 && col < 2048)) v = fsigm(v);
            if (caplen) v *= (t < caplen[row] - 1) ? 1.f : 0.f;
            if (C16) C16[(size_t)row * ldc + col] = f2bf(v);
            else     C [(size_t)row * ldc + col] = v;
        }
    }
}

// ---------------------------------------------------------------------------
// Weight packing: Wp[(kb*Npad + n)*32 + kk] = src[k=kb*32+kk][n], bf16.
// mode 0: single source W1 (K x N1), pad n>=N1 with 0 (Npad >= N1)
// mode 1: n-concat [W1 (K x N1) | W2 (K x N2)], Npad = N1+N2
// mode 2: k-concat [W1 (K1 x N1) ; W2 ((K-K1) x N1)], Npad = N1
// ---------------------------------------------------------------------------
__global__ void pack_kernel(const float* __restrict__ W1, const float* __restrict__ W2,
                            int N1, int N2, int K1, int Npad, int mode,
                            unsigned short* __restrict__ Wp, int total)
{
    int idx = blockIdx.x * 256 + threadIdx.x;
    if (idx >= total) return;
    int kk = idx & 31;
    int r  = idx >> 5;
    int n  = r % Npad;
    int kb = r / Npad;
    int k  = kb * 32 + kk;
    float v = 0.f;
    if (mode == 0) {
        if (n < N1) v = W1[(size_t)k * N1 + n];
    } else if (mode == 1) {
        v = (n < N1) ? W1[(size_t)k * N1 + n] : W2[(size_t)k * N2 + (n - N1)];
    } else {
        v = (k < K1) ? W1[(size_t)k * N1 + n] : W2[(size_t)(k - K1) * N1 + n];
    }
    Wp[idx] = f2bf(v);
}

__global__ void cast_kernel(const float* __restrict__ src,
                            unsigned short* __restrict__ dst, int n)
{
    int i = (blockIdx.x * 256 + threadIdx.x) * 4;
    if (i >= n) return;
    float4 v = *(const float4*)(src + i);
    dst[i]     = f2bf(v.x);
    dst[i + 1] = f2bf(v.y);
    dst[i + 2] = f2bf(v.z);
    dst[i + 3] = f2bf(v.w);
}

__global__ void bias_prep(const float* __restrict__ bfb, const float* __restrict__ bda,
                          const float* __restrict__ bih, const float* __restrict__ bhh,
                          float* __restrict__ bcat, float* __restrict__ bsum)
{
    int i = blockIdx.x * 256 + threadIdx.x;
    if (i < 2048) { bcat[i] = bfb[i]; bsum[i] = bih[i] + bhh[i]; }
    else if (i < 2560) bcat[i] = bda[i - 2048];
}

__global__ void mean_kernel(const float* __restrict__ enc, float* __restrict__ me)
{
    int d = blockIdx.x * 256 + threadIdx.x;
    int b = blockIdx.y;
    const float* p = enc + (size_t)b * NPIX * ENCD + d;
    float s = 0.0f;
    for (int q = 0; q < NPIX; ++q) s += p[(size_t)q * ENCD];
    me[b * ENCD + d] = s * (1.0f / 196.0f);
}

// h0 (bf16 into xcat h-region) + c0 (fp32)
__global__ void inithc_kernel(const float* __restrict__ me,
                              const float* __restrict__ Wh, const float* __restrict__ bh,
                              const float* __restrict__ Wc, const float* __restrict__ bc,
                              unsigned short* __restrict__ xcat, float* __restrict__ c)
{
    int idx = blockIdx.x * 256 + threadIdx.x;  // 0..32767
    int b = idx >> 9, j = idx & 511;
    const float* m = me + b * ENCD;
    float sh = bh[j], sc = bc[j];
    for (int k = 0; k < ENCD; ++k) {
        float mv = m[k];
        sh += mv * Wh[(size_t)k * DECD + j];
        sc += mv * Wc[(size_t)k * DECD + j];
    }
    xcat[(size_t)b * 3072 + 2560 + j] = f2bf(sh);
    c[idx] = sc;
}

__global__ void copy_misc(const int* __restrict__ caps, const int* __restrict__ lens,
                          float* __restrict__ out)
{
    int i = blockIdx.x * 256 + threadIdx.x;
    if (i < CAPS_SZ) out[PRED_SZ + i] = (float)caps[i];
    else if (i < CAPS_SZ + LENS_SZ) out[PRED_SZ + i] = (float)(lens[i - CAPS_SZ] - 1);
}

// ---------------------------------------------------------------------------
// Attention: e = tanh(att_enc16 + adec)@Wf + bf; alpha = softmax(e).
// gadec holds [gate(2048) | adec(512)] per row. One block per batch row.
// ---------------------------------------------------------------------------
__global__ __launch_bounds__(256) void att_kernel(
    const float* __restrict__ gadec,
    const unsigned short* __restrict__ att_enc16,
    const float* __restrict__ Wf, const float* __restrict__ bf_,
    const int* __restrict__ caplen, int t,
    float* __restrict__ alpha_ws, float* __restrict__ alphas_out)
{
    int b = blockIdx.x;
    int tid = threadIdx.x;
    int lane = tid & 63, wid = tid >> 6;
    __shared__ float av[512];
    __shared__ float wv[512];
    __shared__ float es[196];
    __shared__ float r4[4];
    __shared__ float smax, ssum;

    for (int j = tid; j < 512; j += 256) {
        av[j] = gadec[(size_t)b * 2560 + 2048 + j];
        wv[j] = Wf[j];
    }
    __syncthreads();

    float mya[8], myw[8];
#pragma unroll
    for (int i = 0; i < 8; ++i) {
        mya[i] = av[lane * 8 + i];
        myw[i] = wv[lane * 8 + i];
    }

    for (int p = wid; p < NPIX; p += 4) {
        const unsigned short* ae = att_enc16 + ((size_t)(b * NPIX + p)) * 512 + lane * 8;
        short8 e8 = *(const short8*)ae;
        float s = 0.f;
#pragma unroll
        for (int i = 0; i < 8; ++i)
            s += ftanh(bf2f((unsigned short)e8[i]) + mya[i]) * myw[i];
        for (int off = 32; off; off >>= 1) s += __shfl_down(s, off);
        if (lane == 0) es[p] = s + bf_[0];
    }
    __syncthreads();

    float v = (tid < NPIX) ? es[tid] : -1e30f;
    float m = v;
    for (int off = 32; off; off >>= 1) m = fmaxf(m, __shfl_down(m, off));
    if (lane == 0) r4[wid] = m;
    __syncthreads();
    if (tid == 0) smax = fmaxf(fmaxf(r4[0], r4[1]), fmaxf(r4[2], r4[3]));
    __syncthreads();

    float ev = (tid < NPIX) ? __expf(v - smax) : 0.0f;
    float s = ev;
    for (int off = 32; off; off >>= 1) s += __shfl_down(s, off);
    if (lane == 0) r4[wid] = s;
    __syncthreads();
    if (tid == 0) ssum = r4[0] + r4[1] + r4[2] + r4[3];
    __syncthreads();

    if (tid < NPIX) {
        float a = ev / ssum;
        alpha_ws[b * NPIX + tid] = a;
        float mk = (t < caplen[b] - 1) ? 1.0f : 0.0f;
        alphas_out[((size_t)b * TT + t) * NPIX + tid] = a * mk;
    }
}

// ---------------------------------------------------------------------------
// awe partials: part[pg][b][d] = sum_{p in 49-pixel group pg} alpha*enc16
// grid (4, 64), thread handles 8 consecutive d (bf16x8 loads).
// ---------------------------------------------------------------------------
__global__ __launch_bounds__(256) void awe_part_kernel(
    const unsigned short* __restrict__ enc16, const float* __restrict__ alpha,
    float* __restrict__ part)
{
    int pg = blockIdx.x, b = blockIdx.y, tid = threadIdx.x;
    __shared__ float as[49];
    if (tid < 49) as[tid] = alpha[b * NPIX + pg * 49 + tid];
    __syncthreads();
    int d0 = tid * 8;
    float s[8];
#pragma unroll
    for (int j = 0; j < 8; ++j) s[j] = 0.f;
    const unsigned short* e = enc16 + ((size_t)b * NPIX + pg * 49) * ENCD + d0;
    for (int i = 0; i < 49; ++i) {
        short8 v = *(const short8*)(e + (size_t)i * ENCD);
        float a = as[i];
#pragma unroll
        for (int j = 0; j < 8; ++j) s[j] += a * bf2f((unsigned short)v[j]);
    }
    float* o = part + ((size_t)(pg * 64 + b)) * ENCD + d0;
#pragma unroll
    for (int j = 0; j < 8; ++j) o[j] = s[j];
}

// xcat row: [emb(512) | gate*awe(2048) | h(512, written by lstm)]  (bf16)
__global__ __launch_bounds__(256) void xcat_kernel(
    const float* __restrict__ emb, const int* __restrict__ caps, int t,
    const float* __restrict__ part, const float* __restrict__ gadec,
    unsigned short* __restrict__ xcat)
{
    int b = blockIdx.x, tid = threadIdx.x;
    unsigned short* xr = xcat + (size_t)b * 3072;
    int wword = caps[b * MAXLEN + t];
    for (int j = tid; j < 512; j += 256)
        xr[j] = f2bf(emb[(size_t)wword * 512 + j]);
    int d0 = tid * 8;
#pragma unroll
    for (int j = 0; j < 8; ++j) {
        int d = d0 + j;
        float s = part[(size_t)(0 * 64 + b) * ENCD + d] + part[(size_t)(1 * 64 + b) * ENCD + d]
                + part[(size_t)(2 * 64 + b) * ENCD + d] + part[(size_t)(3 * 64 + b) * ENCD + d];
        s *= gadec[(size_t)b * 2560 + d];
        xr[512 + d] = f2bf(s);
    }
}

// LSTM: reduce 4 K-slice partials + bias, gate math, masked c/h update.
// h written as bf16 into xcat h-region.
__global__ __launch_bounds__(256) void lstm_kernel(
    const float* __restrict__ gparts, const float* __restrict__ bsum,
    const int* __restrict__ caplen, int t,
    float* __restrict__ c, unsigned short* __restrict__ xcat)
{
    int idx = blockIdx.x * 256 + threadIdx.x;  // 0..32767
    int b = idx >> 9, j = idx & 511;
    const float* g = gparts + (size_t)b * 2048;
    float gi = bsum[j],        gf = bsum[512 + j];
    float gg = bsum[1024 + j], go = bsum[1536 + j];
#pragma unroll
    for (int s = 0; s < 4; ++s) {
        const float* p = g + (size_t)s * BB * 2048;
        gi += p[j]; gf += p[512 + j]; gg += p[1024 + j]; go += p[1536 + j];
    }
    float cn = fsigm(gf) * c[idx] + fsigm(gi) * ftanh(gg);
    float hn = fsigm(go) * ftanh(cn);
    if (t < caplen[b] - 1) {
        c[idx] = cn;
        xcat[(size_t)b * 3072 + 2560 + j] = f2bf(hn);
    }
}

// ---------------------------------------------------------------------------
extern "C" void kernel_launch(void* const* d_in, const int* in_sizes, int n_in,
                              void* d_out, int out_size, void* d_ws, size_t ws_size,
                              hipStream_t stream)
{
    (void)in_sizes; (void)n_in; (void)out_size; (void)ws_size;
    const float* enc        = (const float*)d_in[0];
    const int*   caps       = (const int*)d_in[1];
    const int*   lens       = (const int*)d_in[2];
    const float* emb        = (const float*)d_in[3];
    const float* W_enc_att  = (const float*)d_in[4];
    const float* b_enc_att  = (const float*)d_in[5];
    const float* W_dec_att  = (const float*)d_in[6];
    const float* b_dec_att  = (const float*)d_in[7];
    const float* W_full_att = (const float*)d_in[8];
    const float* b_full_att = (const float*)d_in[9];
    const float* W_init_h   = (const float*)d_in[10];
    const float* b_init_h   = (const float*)d_in[11];
    const float* W_init_c   = (const float*)d_in[12];
    const float* b_init_c   = (const float*)d_in[13];
    const float* W_fbeta    = (const float*)d_in[14];
    const float* b_fbeta    = (const float*)d_in[15];
    const float* W_ih       = (const float*)d_in[16];
    const float* W_hh       = (const float*)d_in[17];
    const float* b_ih       = (const float*)d_in[18];
    const float* b_hh       = (const float*)d_in[19];
    const float* W_fc       = (const float*)d_in[20];
    const float* b_fc       = (const float*)d_in[21];
    float* out = (float*)d_out;

    // ---- workspace carve-up (16B aligned chunks) ----
    char* p = (char*)d_ws;
    unsigned short* enc16   = (unsigned short*)p; p += (size_t)BB * NPIX * ENCD * 2;   // 51.4MB
    unsigned short* attenc16= (unsigned short*)p; p += (size_t)BB * NPIX * 512 * 2;    // 12.8MB
    unsigned short* WpG     = (unsigned short*)p; p += (size_t)16 * 2560 * 32 * 2;     // 2.6MB  gate|adec K=512 Npad=2560
    unsigned short* WpL     = (unsigned short*)p; p += (size_t)96 * 2048 * 32 * 2;     // 12.6MB gates K=3072 Npad=2048
    unsigned short* WpF     = (unsigned short*)p; p += (size_t)16 * NPADFC * 32 * 2;   // 10.3MB fc K=512 Npad=10048
    unsigned short* WpE     = (unsigned short*)p; p += (size_t)64 * 512 * 32 * 2;      // 2.1MB  enc_att K=2048 Npad=512
    unsigned short* xcat    = (unsigned short*)p; p += (size_t)BB * 3072 * 2;          // 384KB
    float* gadec  = (float*)p; p += (size_t)BB * 2560 * 4;                             // 640KB
    float* gparts = (float*)p; p += (size_t)4 * BB * 2048 * 4;                         // 2MB
    float* c      = (float*)p; p += (size_t)BB * 512 * 4;                              // 128KB
    float* alpha  = (float*)p; p += (size_t)BB * NPIX * 4;                             // 50KB
    float* part   = (float*)p; p += (size_t)4 * BB * ENCD * 4;                         // 2MB
    float* me     = (float*)p; p += (size_t)BB * ENCD * 4;                             // 512KB
    float* bcat   = (float*)p; p += 2560 * 4;
    float* bsum   = (float*)p; p += 2048 * 4;

    // ---- setup ----
    {
        int n = BB * NPIX * ENCD;
        cast_kernel<<<(n / 4 + 255) / 256, 256, 0, stream>>>(enc, enc16, n);
    }
    { int tot = 16 * 2560 * 32;
      pack_kernel<<<(tot + 255) / 256, 256, 0, stream>>>(W_fbeta, W_dec_att, 2048, 512, 0, 2560, 1, WpG, tot); }
    { int tot = 96 * 2048 * 32;
      pack_kernel<<<(tot + 255) / 256, 256, 0, stream>>>(W_ih, W_hh, 2048, 2048, 2560, 2048, 2, WpL, tot); }
    { int tot = 16 * NPADFC * 32;
      pack_kernel<<<(tot + 255) / 256, 256, 0, stream>>>(W_fc, nullptr, VOCAB_N, 0, 0, NPADFC, 0, WpF, tot); }
    { int tot = 64 * 512 * 32;
      pack_kernel<<<(tot + 255) / 256, 256, 0, stream>>>(W_enc_att, nullptr, 512, 0, 0, 512, 0, WpE, tot); }
    bias_prep<<<10, 256, 0, stream>>>(b_fbeta, b_dec_att, b_ih, b_hh, bcat, bsum);
    mean_kernel<<<dim3(8, 64), 256, 0, stream>>>(enc, me);
    inithc_kernel<<<128, 256, 0, stream>>>(me, W_init_h, b_init_h, W_init_c, b_init_c, xcat, c);
    // att_enc16 = enc16 @ W_enc_att + b  (bf16 out), M=12544
    gemm_mfma<<<dim3(8, 196, 1), 256, 0, stream>>>(
        enc16, ENCD, WpE, 512, 64, 0, nullptr, attenc16, 512,
        b_enc_att, 512, 0, nullptr, 0);
    copy_misc<<<14, 256, 0, stream>>>(caps, lens, out);

    const unsigned short* h16 = xcat + 2560;  // lda = 3072

    // ---- decode loop ----
    for (int t = 0; t < TT; ++t) {
        // gadec = [sigmoid(h@Wfbeta+b) | h@Wd+bd]
        gemm_mfma<<<dim3(40, 1, 1), 256, 0, stream>>>(
            h16, 3072, WpG, 2560, 16, 0, gadec, nullptr, 2560,
            bcat, 2560, 2, nullptr, 0);
        att_kernel<<<64, 256, 0, stream>>>(gadec, attenc16, W_full_att, b_full_att,
                                           lens, t, alpha, out + ALPHAS_OFF);
        awe_part_kernel<<<dim3(4, 64), 256, 0, stream>>>(enc16, alpha, part);
        xcat_kernel<<<64, 256, 0, stream>>>(emb, caps, t, part, gadec, xcat);
        // gates partials: 4 K-slices of K=3072
        gemm_mfma<<<dim3(32, 1, 4), 256, 0, stream>>>(
            xcat, 3072, WpL, 2048, 24, (long)BB * 2048, gparts, nullptr, 2048,
            nullptr, 2048, 0, nullptr, 0);
        lstm_kernel<<<128, 256, 0, stream>>>(gparts, bsum, lens, t, c, xcat);
        // preds = (h@Wfc+b)*mask
        gemm_mfma<<<dim3(157, 1, 1), 256, 0, stream>>>(
            h16, 3072, WpF, NPADFC, 16, 0, out + (size_t)t * VOCAB_N, nullptr,
            (long)TT * VOCAB_N, b_fc, VOCAB_N, 0, lens, t);
    }
}